// Round 4
// baseline (288.534 us; speedup 1.0000x reference)
//
#include <hip/hip_runtime.h>

// MultiBoxLoss (SSD). B=128, P=8732, C=21, N=16 (runtime-derived).
// R4: k_match (1 block/batch, 79us, 21% occ) split into two fully-parallel
// kernels: k_bestprior (wave per (b,n) object-argmax) + k_assign (thread per
// (b,p): best-object, override scan, label, encode, SmoothL1).
// K2 k_conf : per-prior CE, LDS-staged coalesced score reads (the 94MB pass)
// K3 k_hard : per-batch exact top-k, 4-ary search on float bits + ballot counts
// K4 k_final: sum partials, write scalar.
// ws: slot[B*P] f32 (labels -> conf_neg), npos[B] i32 (atomic, memset 0),
//     pfo[B*N] i32, locpart[B*nchunk] f32, possum[nconf] f32, hardsum[B] f32.

#define MAXN 16

__device__ __forceinline__ float sl1f(float d) {
    float ad = fabsf(d);
    return ad < 1.0f ? 0.5f * d * d : ad - 0.5f;
}

// One wave per (b,n): argmax over P priors of IoU(box[b,n], prior[p]).
// First-index tie-break: per-lane strict > over ascending p, cross-lane
// prefers larger v then smaller index.
__global__ __launch_bounds__(256) void k_bestprior(
    const float* __restrict__ boxes,   // [B,N,4] xy
    const float* __restrict__ priors,  // [P,4] cxcy
    int P, int BN,
    int* __restrict__ pfo)             // [B*N]
{
    const int lane = threadIdx.x & 63, wid = threadIdx.x >> 6;
    const int id = blockIdx.x * (blockDim.x >> 6) + wid;   // = b*N + n
    if (id >= BN) return;
    const float* bp = boxes + (size_t)id * 4;
    const float bx1 = bp[0], by1 = bp[1], bx2 = bp[2], by2 = bp[3];
    const float ba = (bx2 - bx1) * (by2 - by1);
    float v = -1.0f; int i = 0x7fffffff;
    for (int p = lane; p < P; p += 64) {
        float4 pr = ((const float4*)priors)[p];
        float px1 = pr.x - pr.z * 0.5f, py1 = pr.y - pr.w * 0.5f;
        float px2 = pr.x + pr.z * 0.5f, py2 = pr.y + pr.w * 0.5f;
        float parea = (px2 - px1) * (py2 - py1);
        float iw = fmaxf(fminf(bx2, px2) - fmaxf(bx1, px1), 0.0f);
        float ih = fmaxf(fminf(by2, py2) - fmaxf(by1, py1), 0.0f);
        float inter = iw * ih;
        float iou = inter / (ba + parea - inter);
        if (iou > v) { v = iou; i = p; }
    }
#pragma unroll
    for (int off = 32; off > 0; off >>= 1) {
        float ov = __shfl_down(v, off);
        int   oi = __shfl_down(i, off);
        if (ov > v || (ov == v && oi < i)) { v = ov; i = oi; }
    }
    if (lane == 0) pfo[id] = i;
}

// Thread per (b,p): best object (argmax axis=0, first-index ties), override
// (scan n ascending, last match wins = sequential scatter order), label,
// gcxgcy encode + SmoothL1 for positives.
__global__ __launch_bounds__(256) void k_assign(
    const float* __restrict__ plocs,   // [B,P,4]
    const float* __restrict__ boxes,   // [B,N,4]
    const int*   __restrict__ labels,  // [B,N]
    const float* __restrict__ priors,  // [P,4]
    const int*   __restrict__ pfo,     // [B*N]
    int P, int N, int nchunk,
    int*   __restrict__ cls_out,       // [B,P]
    int*   __restrict__ npos,          // [B] (atomic)
    float* __restrict__ locpart)       // [B*nchunk]
{
    __shared__ float sx1[MAXN], sy1[MAXN], sx2[MAXN], sy2[MAXN], barea[MAXN];
    __shared__ int   blab[MAXN], spfo[MAXN];
    __shared__ float redf[4];
    __shared__ int   redi[4];

    const int b = blockIdx.y;
    const int tid = threadIdx.x;
    const int lane = tid & 63, wid = tid >> 6;
    if (N > MAXN) N = MAXN;

    if (tid < N) {
        const float* bp = boxes + ((size_t)b * N + tid) * 4;
        float x1 = bp[0], y1 = bp[1], x2 = bp[2], y2 = bp[3];
        sx1[tid] = x1; sy1[tid] = y1; sx2[tid] = x2; sy2[tid] = y2;
        barea[tid] = (x2 - x1) * (y2 - y1);
        blab[tid] = labels[(size_t)b * N + tid];
        spfo[tid] = pfo[b * N + tid];
    }
    __syncthreads();

    const int p = blockIdx.x * 256 + tid;
    float locs = 0.0f; int np = 0;
    if (p < P) {
        float4 pr = ((const float4*)priors)[p];
        float px1 = pr.x - pr.z * 0.5f, py1 = pr.y - pr.w * 0.5f;
        float px2 = pr.x + pr.z * 0.5f, py2 = pr.y + pr.w * 0.5f;
        float parea = (px2 - px1) * (py2 - py1);
        float best = -1.0f; int bestn = 0;
#pragma unroll
        for (int n = 0; n < MAXN; n++) {
            if (n < N) {
                float iw = fmaxf(fminf(sx2[n], px2) - fmaxf(sx1[n], px1), 0.0f);
                float ih = fmaxf(fminf(sy2[n], py2) - fmaxf(sy1[n], py1), 0.0f);
                float inter = iw * ih;
                float iou = inter / (barea[n] + parea - inter);
                if (iou > best) { best = iou; bestn = n; }
            }
        }
        // override: last n with pfo[n]==p wins (matches sequential scatter)
#pragma unroll
        for (int n = 0; n < MAXN; n++) {
            if (n < N && spfo[n] == p) { bestn = n; best = 1.0f; }
        }
        int lab = (best < 0.5f) ? 0 : blab[bestn];
        cls_out[(size_t)b * P + p] = lab;
        if (lab != 0) {
            np = 1;
            int n = bestn;
            float cx = (sx1[n] + sx2[n]) * 0.5f, cy = (sy1[n] + sy2[n]) * 0.5f;
            float w = sx2[n] - sx1[n], h = sy2[n] - sy1[n];
            float g0 = (cx - pr.x) / (pr.z / 10.0f);
            float g1 = (cy - pr.y) / (pr.w / 10.0f);
            float g2 = logf(w / pr.z) * 5.0f;
            float g3 = logf(h / pr.w) * 5.0f;
            float4 pl = ((const float4*)plocs)[(size_t)b * P + p];
            locs = sl1f(pl.x - g0) + sl1f(pl.y - g1) + sl1f(pl.z - g2) + sl1f(pl.w - g3);
        }
    }
#pragma unroll
    for (int off = 32; off > 0; off >>= 1) {
        locs += __shfl_down(locs, off);
        np   += __shfl_down(np, off);
    }
    if (lane == 0) { redf[wid] = locs; redi[wid] = np; }
    __syncthreads();
    if (tid == 0) {
        float L = redf[0] + redf[1] + redf[2] + redf[3];
        int   c = redi[0] + redi[1] + redi[2] + redi[3];
        if (c) atomicAdd(&npos[b], c);          // int atomic: deterministic
        locpart[b * nchunk + blockIdx.x] = L;   // fixed slot: deterministic
    }
}

__global__ __launch_bounds__(256) void k_conf(
    const float* __restrict__ scores, // [total, C]
    int total, int C,
    float* __restrict__ slot,         // in: labels(int), out: conf_neg(float)
    float* __restrict__ possum)       // [gridDim.x]
{
    extern __shared__ float sh[];     // 256*C floats
    __shared__ float redf[4];
    const int tid = threadIdx.x;
    const int lane = tid & 63, wid = tid >> 6;
    const int blk = blockIdx.x;
    const int row0 = blk * 256;

    const size_t f4base = (size_t)row0 * C / 4;
    const size_t f4total = (size_t)total * C / 4;
    const int f4blk = 64 * C;  // 256*C/4
    const float4* __restrict__ s4 = (const float4*)scores;
    for (int j = tid; j < f4blk; j += 256) {
        size_t g = f4base + j;
        if (g < f4total) ((float4*)sh)[j] = s4[g];
    }
    __syncthreads();

    const int idx = row0 + tid;
    float posc = 0.0f;
    if (idx < total) {
        int lab = ((const int*)slot)[idx];
        const float* r = sh + tid * C;
        float m = -3.402823466e38f;
        for (int c = 0; c < C; c++) m = fmaxf(m, r[c]);
        float sum = 0.0f;
        for (int c = 0; c < C; c++) sum += __expf(r[c] - m);
        float conf = m + __logf(sum) - r[lab];   // -log_softmax[lab]
        if (lab != 0) { posc = conf; conf = 0.0f; }
        slot[idx] = conf;
    }
#pragma unroll
    for (int off = 32; off > 0; off >>= 1) posc += __shfl_down(posc, off);
    if (lane == 0) redf[wid] = posc;
    __syncthreads();
    if (tid == 0) possum[blk] = redf[0] + redf[1] + redf[2] + redf[3];
}

__global__ __launch_bounds__(1024) void k_hard(
    const float* __restrict__ conf,  // [B,P] conf_neg (>=0; 0 at positives)
    const int* __restrict__ npos,
    int P,
    float* __restrict__ hardsum)     // [B]
{
    extern __shared__ unsigned int u[];   // P uints
    __shared__ int   redi[16 * 3];
    __shared__ float redf2[16];
    __shared__ int   redi2[16];
    const int b = blockIdx.x, tid = threadIdx.x;
    const int lane = tid & 63, wid = tid >> 6;
    const int nthr = blockDim.x, nw = nthr >> 6;
    long long kk = (long long)npos[b] * 3;
    int k = kk > P ? P : (int)kk;
    if (k <= 0) {
        if (tid == 0) hardsum[b] = 0.0f;
        return;
    }

    for (int p = tid; p < P; p += nthr) u[p] = __float_as_uint(conf[(size_t)b * P + p]);
    __syncthreads();

    // largest bit pattern t with count(x >= t) >= k == exact k-th largest.
    // 4-ary search, counts via ballot/popc (active lanes are a prefix).
    unsigned lo = 0u, hi = 0x7F800000u;
    while (lo < hi) {
        unsigned span = hi - lo;
        if (span >= 8) {
            unsigned q = span >> 2;
            unsigned m1 = lo + q, m2 = lo + 2 * q, m3 = lo + 3 * q;
            int c1 = 0, c2 = 0, c3 = 0;
            for (int p = tid; p < P; p += nthr) {
                unsigned v = u[p];
                c1 += (int)__popcll(__ballot(v >= m1));
                c2 += (int)__popcll(__ballot(v >= m2));
                c3 += (int)__popcll(__ballot(v >= m3));
            }
            if (lane == 0) {
                redi[wid * 3 + 0] = c1; redi[wid * 3 + 1] = c2; redi[wid * 3 + 2] = c3;
            }
            __syncthreads();
            int C1 = 0, C2 = 0, C3 = 0;
            for (int w = 0; w < nw; w++) {
                C1 += redi[w * 3 + 0]; C2 += redi[w * 3 + 1]; C3 += redi[w * 3 + 2];
            }
            __syncthreads();
            if      (C3 >= k) lo = m3;
            else if (C2 >= k) { lo = m2; hi = m3 - 1; }
            else if (C1 >= k) { lo = m1; hi = m2 - 1; }
            else              hi = m1 - 1;
        } else {
            unsigned mid = lo + ((span + 1) >> 1);
            int c = 0;
            for (int p = tid; p < P; p += nthr)
                c += (int)__popcll(__ballot(u[p] >= mid));
            if (lane == 0) redi[wid * 3] = c;
            __syncthreads();
            int Cc = 0;
            for (int w = 0; w < nw; w++) Cc += redi[w * 3];
            __syncthreads();
            if (Cc >= k) lo = mid; else hi = mid - 1;
        }
    }

    float t = __uint_as_float(lo);
    float sgt = 0.0f; int cgt = 0;
    for (int p = tid; p < P; p += nthr) {
        float v = __uint_as_float(u[p]);
        if (v > t) { sgt += v; cgt++; }
    }
#pragma unroll
    for (int off = 32; off > 0; off >>= 1) {
        sgt += __shfl_down(sgt, off);
        cgt += __shfl_down(cgt, off);
    }
    if (lane == 0) { redf2[wid] = sgt; redi2[wid] = cgt; }
    __syncthreads();
    if (tid == 0) {
        float S = 0.0f; int Cg = 0;
        for (int w = 0; w < nw; w++) { S += redf2[w]; Cg += redi2[w]; }
        hardsum[b] = S + (float)(k - Cg) * t;
    }
}

__global__ __launch_bounds__(1024) void k_final(
    const int* __restrict__ npos, const float* __restrict__ locpart,
    const float* __restrict__ hardsum, const float* __restrict__ possum,
    int B, int nloc, int nconf, float* __restrict__ out)
{
    const int tid = threadIdx.x, lane = tid & 63, wid = tid >> 6;
    __shared__ float rf[3 * 16];
    __shared__ int   ri[16];
    float lp = 0, pp = 0, hp = 0; int np = 0;
    for (int i = tid; i < B; i += 1024) { np += npos[i]; hp += hardsum[i]; }
    for (int i = tid; i < nloc; i += 1024) lp += locpart[i];
    for (int i = tid; i < nconf; i += 1024) pp += possum[i];
#pragma unroll
    for (int off = 32; off > 0; off >>= 1) {
        np += __shfl_down(np, off); lp += __shfl_down(lp, off);
        pp += __shfl_down(pp, off); hp += __shfl_down(hp, off);
    }
    if (lane == 0) { ri[wid] = np; rf[wid] = lp; rf[16 + wid] = pp; rf[32 + wid] = hp; }
    __syncthreads();
    if (tid == 0) {
        int nw = (int)(blockDim.x >> 6);
        float L = 0, Pp = 0, H = 0; int Np = 0;
        for (int w = 0; w < nw; w++) { Np += ri[w]; L += rf[w]; Pp += rf[16 + w]; H += rf[32 + w]; }
        float npf = (float)Np;
        out[0] = (H + Pp) / npf + L / (npf * 4.0f);
    }
}

extern "C" void kernel_launch(void* const* d_in, const int* in_sizes, int n_in,
                              void* d_out, int out_size, void* d_ws, size_t ws_size,
                              hipStream_t stream)
{
    const float* plocs  = (const float*)d_in[0];
    const float* scores = (const float*)d_in[1];
    const float* boxes  = (const float*)d_in[2];
    const int*   labels = (const int*)d_in[3];
    const float* priors = (const float*)d_in[4];

    int P = in_sizes[4] / 4;
    int B = in_sizes[0] / (P * 4);
    int C = in_sizes[1] / (in_sizes[0] / 4);
    int N = in_sizes[3] / B;
    int total = B * P;
    int nconf = (total + 255) / 256;
    int nchunk = (P + 255) / 256;
    int BN = B * N;

    char* w = (char*)d_ws;
    float* slot    = (float*)w;  w += (size_t)total * sizeof(float);
    int*   npos    = (int*)w;    w += (size_t)B * sizeof(int);
    int*   pfo     = (int*)w;    w += (size_t)BN * sizeof(int);
    float* locpart = (float*)w;  w += (size_t)B * nchunk * sizeof(float);
    float* hardsum = (float*)w;  w += (size_t)B * sizeof(float);
    float* possum  = (float*)w;

    hipMemsetAsync(npos, 0, (size_t)B * sizeof(int), stream);

    k_bestprior<<<(BN + 3) / 4, 256, 0, stream>>>(boxes, priors, P, BN, pfo);

    dim3 ga(nchunk, B);
    k_assign<<<ga, 256, 0, stream>>>(plocs, boxes, labels, priors, pfo,
                                     P, N, nchunk, (int*)slot, npos, locpart);

    size_t sm2 = (size_t)256 * C * sizeof(float);
    k_conf<<<nconf, 256, sm2, stream>>>(scores, total, C, slot, possum);

    k_hard<<<B, 1024, (size_t)P * sizeof(unsigned int), stream>>>(slot, npos, P, hardsum);

    k_final<<<1, 1024, 0, stream>>>(npos, locpart, hardsum, possum,
                                    B, B * nchunk, nconf, (float*)d_out);
}

// Round 5
// 238.727 us; speedup vs baseline: 1.2086x; 1.2086x over previous
//
#include <hip/hip_runtime.h>

// MultiBoxLoss (SSD). B=128, P=8732, C=21, N=16 (runtime-derived).
// R5: k_bestprior restructured from wave-per-(b,n) (512 blocks, latency-bound,
//     72us) to BLOCK-per-(b,n) (2048 blocks, full occupancy). Also absorbs
//     npos zeroing (drops the memset dispatch).
// k_assign: thread per (b,p): best-object, override scan, label, encode, SL1.
// k_conf  : per-prior CE, LDS-staged coalesced score reads (the 94MB pass).
// k_hard  : per-batch exact top-k, 4-ary search on float bits + ballot counts.
// k_final : sum partials, write scalar.
// ws: slot[B*P] f32 (labels -> conf_neg), npos[B] i32 (zeroed by k_bestprior),
//     pfo[B*N] i32, locpart[B*nchunk] f32, possum[nconf] f32, hardsum[B] f32.

#define MAXN 16

__device__ __forceinline__ float sl1f(float d) {
    float ad = fabsf(d);
    return ad < 1.0f ? 0.5f * d * d : ad - 0.5f;
}

// One BLOCK (256 thr) per (b,n): argmax over P priors of IoU(box[b,n], prior).
// First-index ties: per-lane strict > over ascending p; cross-lane/wave reduce
// prefers larger v then smaller index.
__global__ __launch_bounds__(256) void k_bestprior(
    const float* __restrict__ boxes,   // [B,N,4] xy
    const float* __restrict__ priors,  // [P,4] cxcy
    int P, int N,
    int* __restrict__ pfo,             // [B*N]
    int* __restrict__ npos)            // [B] zeroed here (used by k_assign later)
{
    __shared__ float rv[4];
    __shared__ int   riq[4];
    const int id = blockIdx.x;               // b*N + n
    const int tid = threadIdx.x;
    const int lane = tid & 63, wid = tid >> 6;

    if (tid == 0 && (id % N) == 0) npos[id / N] = 0;

    const float* bp = boxes + (size_t)id * 4;
    const float bx1 = bp[0], by1 = bp[1], bx2 = bp[2], by2 = bp[3];
    const float ba = (bx2 - bx1) * (by2 - by1);

    float v = -1.0f; int i = 0x7fffffff;
    for (int p = tid; p < P; p += 256) {
        float4 pr = ((const float4*)priors)[p];
        float px1 = pr.x - pr.z * 0.5f, py1 = pr.y - pr.w * 0.5f;
        float px2 = pr.x + pr.z * 0.5f, py2 = pr.y + pr.w * 0.5f;
        float parea = (px2 - px1) * (py2 - py1);
        float iw = fmaxf(fminf(bx2, px2) - fmaxf(bx1, px1), 0.0f);
        float ih = fmaxf(fminf(by2, py2) - fmaxf(by1, py1), 0.0f);
        float inter = iw * ih;
        float iou = inter / (ba + parea - inter);
        if (iou > v) { v = iou; i = p; }      // ascending p => first index
    }
#pragma unroll
    for (int off = 32; off > 0; off >>= 1) {
        float ov = __shfl_down(v, off);
        int   oi = __shfl_down(i, off);
        if (ov > v || (ov == v && oi < i)) { v = ov; i = oi; }
    }
    if (lane == 0) { rv[wid] = v; riq[wid] = i; }
    __syncthreads();
    if (tid == 0) {
        for (int w = 1; w < 4; w++) {
            float ov = rv[w]; int oi = riq[w];
            if (ov > v || (ov == v && oi < i)) { v = ov; i = oi; }
        }
        pfo[id] = i;
    }
}

// Thread per (b,p): best object (argmax axis=0, first-index ties), override
// (scan n ascending, last match wins = sequential scatter order), label,
// gcxgcy encode + SmoothL1 for positives.
__global__ __launch_bounds__(256) void k_assign(
    const float* __restrict__ plocs,   // [B,P,4]
    const float* __restrict__ boxes,   // [B,N,4]
    const int*   __restrict__ labels,  // [B,N]
    const float* __restrict__ priors,  // [P,4]
    const int*   __restrict__ pfo,     // [B*N]
    int P, int N, int nchunk,
    int*   __restrict__ cls_out,       // [B,P]
    int*   __restrict__ npos,          // [B] (atomic)
    float* __restrict__ locpart)       // [B*nchunk]
{
    __shared__ float sx1[MAXN], sy1[MAXN], sx2[MAXN], sy2[MAXN], barea[MAXN];
    __shared__ int   blab[MAXN], spfo[MAXN];
    __shared__ float redf[4];
    __shared__ int   redi[4];

    const int b = blockIdx.y;
    const int tid = threadIdx.x;
    const int lane = tid & 63, wid = tid >> 6;
    if (N > MAXN) N = MAXN;

    if (tid < N) {
        const float* bp = boxes + ((size_t)b * N + tid) * 4;
        float x1 = bp[0], y1 = bp[1], x2 = bp[2], y2 = bp[3];
        sx1[tid] = x1; sy1[tid] = y1; sx2[tid] = x2; sy2[tid] = y2;
        barea[tid] = (x2 - x1) * (y2 - y1);
        blab[tid] = labels[(size_t)b * N + tid];
        spfo[tid] = pfo[b * N + tid];
    }
    __syncthreads();

    const int p = blockIdx.x * 256 + tid;
    float locs = 0.0f; int np = 0;
    if (p < P) {
        float4 pr = ((const float4*)priors)[p];
        float px1 = pr.x - pr.z * 0.5f, py1 = pr.y - pr.w * 0.5f;
        float px2 = pr.x + pr.z * 0.5f, py2 = pr.y + pr.w * 0.5f;
        float parea = (px2 - px1) * (py2 - py1);
        float best = -1.0f; int bestn = 0;
#pragma unroll
        for (int n = 0; n < MAXN; n++) {
            if (n < N) {
                float iw = fmaxf(fminf(sx2[n], px2) - fmaxf(sx1[n], px1), 0.0f);
                float ih = fmaxf(fminf(sy2[n], py2) - fmaxf(sy1[n], py1), 0.0f);
                float inter = iw * ih;
                float iou = inter / (barea[n] + parea - inter);
                if (iou > best) { best = iou; bestn = n; }
            }
        }
        // override: last n with pfo[n]==p wins (matches sequential scatter)
#pragma unroll
        for (int n = 0; n < MAXN; n++) {
            if (n < N && spfo[n] == p) { bestn = n; best = 1.0f; }
        }
        int lab = (best < 0.5f) ? 0 : blab[bestn];
        cls_out[(size_t)b * P + p] = lab;
        if (lab != 0) {
            np = 1;
            int n = bestn;
            float cx = (sx1[n] + sx2[n]) * 0.5f, cy = (sy1[n] + sy2[n]) * 0.5f;
            float w = sx2[n] - sx1[n], h = sy2[n] - sy1[n];
            float g0 = (cx - pr.x) / (pr.z / 10.0f);
            float g1 = (cy - pr.y) / (pr.w / 10.0f);
            float g2 = logf(w / pr.z) * 5.0f;
            float g3 = logf(h / pr.w) * 5.0f;
            float4 pl = ((const float4*)plocs)[(size_t)b * P + p];
            locs = sl1f(pl.x - g0) + sl1f(pl.y - g1) + sl1f(pl.z - g2) + sl1f(pl.w - g3);
        }
    }
#pragma unroll
    for (int off = 32; off > 0; off >>= 1) {
        locs += __shfl_down(locs, off);
        np   += __shfl_down(np, off);
    }
    if (lane == 0) { redf[wid] = locs; redi[wid] = np; }
    __syncthreads();
    if (tid == 0) {
        float L = redf[0] + redf[1] + redf[2] + redf[3];
        int   c = redi[0] + redi[1] + redi[2] + redi[3];
        if (c) atomicAdd(&npos[b], c);          // int atomic: deterministic
        locpart[b * nchunk + blockIdx.x] = L;   // fixed slot: deterministic
    }
}

__global__ __launch_bounds__(256) void k_conf(
    const float* __restrict__ scores, // [total, C]
    int total, int C,
    float* __restrict__ slot,         // in: labels(int), out: conf_neg(float)
    float* __restrict__ possum)       // [gridDim.x]
{
    extern __shared__ float sh[];     // 256*C floats
    __shared__ float redf[4];
    const int tid = threadIdx.x;
    const int lane = tid & 63, wid = tid >> 6;
    const int blk = blockIdx.x;
    const int row0 = blk * 256;

    const size_t f4base = (size_t)row0 * C / 4;
    const size_t f4total = (size_t)total * C / 4;
    const int f4blk = 64 * C;  // 256*C/4
    const float4* __restrict__ s4 = (const float4*)scores;
    for (int j = tid; j < f4blk; j += 256) {
        size_t g = f4base + j;
        if (g < f4total) ((float4*)sh)[j] = s4[g];
    }
    __syncthreads();

    const int idx = row0 + tid;
    float posc = 0.0f;
    if (idx < total) {
        int lab = ((const int*)slot)[idx];
        const float* r = sh + tid * C;
        float m = -3.402823466e38f;
        for (int c = 0; c < C; c++) m = fmaxf(m, r[c]);
        float sum = 0.0f;
        for (int c = 0; c < C; c++) sum += __expf(r[c] - m);
        float conf = m + __logf(sum) - r[lab];   // -log_softmax[lab]
        if (lab != 0) { posc = conf; conf = 0.0f; }
        slot[idx] = conf;
    }
#pragma unroll
    for (int off = 32; off > 0; off >>= 1) posc += __shfl_down(posc, off);
    if (lane == 0) redf[wid] = posc;
    __syncthreads();
    if (tid == 0) possum[blk] = redf[0] + redf[1] + redf[2] + redf[3];
}

__global__ __launch_bounds__(1024) void k_hard(
    const float* __restrict__ conf,  // [B,P] conf_neg (>=0; 0 at positives)
    const int* __restrict__ npos,
    int P,
    float* __restrict__ hardsum)     // [B]
{
    extern __shared__ unsigned int u[];   // P uints
    __shared__ int   redi[16 * 3];
    __shared__ float redf2[16];
    __shared__ int   redi2[16];
    const int b = blockIdx.x, tid = threadIdx.x;
    const int lane = tid & 63, wid = tid >> 6;
    const int nthr = blockDim.x, nw = nthr >> 6;
    long long kk = (long long)npos[b] * 3;
    int k = kk > P ? P : (int)kk;
    if (k <= 0) {
        if (tid == 0) hardsum[b] = 0.0f;
        return;
    }

    for (int p = tid; p < P; p += nthr) u[p] = __float_as_uint(conf[(size_t)b * P + p]);
    __syncthreads();

    // largest bit pattern t with count(x >= t) >= k == exact k-th largest.
    // 4-ary search, counts via ballot/popc (active lanes are a prefix).
    unsigned lo = 0u, hi = 0x7F800000u;
    while (lo < hi) {
        unsigned span = hi - lo;
        if (span >= 8) {
            unsigned q = span >> 2;
            unsigned m1 = lo + q, m2 = lo + 2 * q, m3 = lo + 3 * q;
            int c1 = 0, c2 = 0, c3 = 0;
            for (int p = tid; p < P; p += nthr) {
                unsigned v = u[p];
                c1 += (int)__popcll(__ballot(v >= m1));
                c2 += (int)__popcll(__ballot(v >= m2));
                c3 += (int)__popcll(__ballot(v >= m3));
            }
            if (lane == 0) {
                redi[wid * 3 + 0] = c1; redi[wid * 3 + 1] = c2; redi[wid * 3 + 2] = c3;
            }
            __syncthreads();
            int C1 = 0, C2 = 0, C3 = 0;
            for (int w = 0; w < nw; w++) {
                C1 += redi[w * 3 + 0]; C2 += redi[w * 3 + 1]; C3 += redi[w * 3 + 2];
            }
            __syncthreads();
            if      (C3 >= k) lo = m3;
            else if (C2 >= k) { lo = m2; hi = m3 - 1; }
            else if (C1 >= k) { lo = m1; hi = m2 - 1; }
            else              hi = m1 - 1;
        } else {
            unsigned mid = lo + ((span + 1) >> 1);
            int c = 0;
            for (int p = tid; p < P; p += nthr)
                c += (int)__popcll(__ballot(u[p] >= mid));
            if (lane == 0) redi[wid * 3] = c;
            __syncthreads();
            int Cc = 0;
            for (int w = 0; w < nw; w++) Cc += redi[w * 3];
            __syncthreads();
            if (Cc >= k) lo = mid; else hi = mid - 1;
        }
    }

    float t = __uint_as_float(lo);
    float sgt = 0.0f; int cgt = 0;
    for (int p = tid; p < P; p += nthr) {
        float v = __uint_as_float(u[p]);
        if (v > t) { sgt += v; cgt++; }
    }
#pragma unroll
    for (int off = 32; off > 0; off >>= 1) {
        sgt += __shfl_down(sgt, off);
        cgt += __shfl_down(cgt, off);
    }
    if (lane == 0) { redf2[wid] = sgt; redi2[wid] = cgt; }
    __syncthreads();
    if (tid == 0) {
        float S = 0.0f; int Cg = 0;
        for (int w = 0; w < nw; w++) { S += redf2[w]; Cg += redi2[w]; }
        hardsum[b] = S + (float)(k - Cg) * t;
    }
}

__global__ __launch_bounds__(1024) void k_final(
    const int* __restrict__ npos, const float* __restrict__ locpart,
    const float* __restrict__ hardsum, const float* __restrict__ possum,
    int B, int nloc, int nconf, float* __restrict__ out)
{
    const int tid = threadIdx.x, lane = tid & 63, wid = tid >> 6;
    __shared__ float rf[3 * 16];
    __shared__ int   ri[16];
    float lp = 0, pp = 0, hp = 0; int np = 0;
    for (int i = tid; i < B; i += 1024) { np += npos[i]; hp += hardsum[i]; }
    for (int i = tid; i < nloc; i += 1024) lp += locpart[i];
    for (int i = tid; i < nconf; i += 1024) pp += possum[i];
#pragma unroll
    for (int off = 32; off > 0; off >>= 1) {
        np += __shfl_down(np, off); lp += __shfl_down(lp, off);
        pp += __shfl_down(pp, off); hp += __shfl_down(hp, off);
    }
    if (lane == 0) { ri[wid] = np; rf[wid] = lp; rf[16 + wid] = pp; rf[32 + wid] = hp; }
    __syncthreads();
    if (tid == 0) {
        int nw = (int)(blockDim.x >> 6);
        float L = 0, Pp = 0, H = 0; int Np = 0;
        for (int w = 0; w < nw; w++) { Np += ri[w]; L += rf[w]; Pp += rf[16 + w]; H += rf[32 + w]; }
        float npf = (float)Np;
        out[0] = (H + Pp) / npf + L / (npf * 4.0f);
    }
}

extern "C" void kernel_launch(void* const* d_in, const int* in_sizes, int n_in,
                              void* d_out, int out_size, void* d_ws, size_t ws_size,
                              hipStream_t stream)
{
    const float* plocs  = (const float*)d_in[0];
    const float* scores = (const float*)d_in[1];
    const float* boxes  = (const float*)d_in[2];
    const int*   labels = (const int*)d_in[3];
    const float* priors = (const float*)d_in[4];

    int P = in_sizes[4] / 4;
    int B = in_sizes[0] / (P * 4);
    int C = in_sizes[1] / (in_sizes[0] / 4);
    int N = in_sizes[3] / B;
    int total = B * P;
    int nconf = (total + 255) / 256;
    int nchunk = (P + 255) / 256;
    int BN = B * N;

    char* w = (char*)d_ws;
    float* slot    = (float*)w;  w += (size_t)total * sizeof(float);
    int*   npos    = (int*)w;    w += (size_t)B * sizeof(int);
    int*   pfo     = (int*)w;    w += (size_t)BN * sizeof(int);
    float* locpart = (float*)w;  w += (size_t)B * nchunk * sizeof(float);
    float* hardsum = (float*)w;  w += (size_t)B * sizeof(float);
    float* possum  = (float*)w;

    k_bestprior<<<BN, 256, 0, stream>>>(boxes, priors, P, N, pfo, npos);

    dim3 ga(nchunk, B);
    k_assign<<<ga, 256, 0, stream>>>(plocs, boxes, labels, priors, pfo,
                                     P, N, nchunk, (int*)slot, npos, locpart);

    size_t sm2 = (size_t)256 * C * sizeof(float);
    k_conf<<<nconf, 256, sm2, stream>>>(scores, total, C, slot, possum);

    k_hard<<<B, 1024, (size_t)P * sizeof(unsigned int), stream>>>(slot, npos, P, hardsum);

    k_final<<<1, 1024, 0, stream>>>(npos, locpart, hardsum, possum,
                                    B, B * nchunk, nconf, (float*)d_out);
}

// Round 6
// 221.374 us; speedup vs baseline: 1.3034x; 1.0784x over previous
//
#include <hip/hip_runtime.h>

// MultiBoxLoss (SSD). B=128, P=8732, C=21, N=16 (runtime-derived).
// R6: k_assign fused into k_conf (k_fused): matching VALU hides under the
//     94MB score stream; kills a dispatch + cls_out round-trip.
//     k_hard made register-resident (no per-round LDS reads).
// k_bestprior: block per (b,n) prior-argmax; zeroes npos.
// k_fused   : thread per (b,p): match label + CE + SL1 + conf_neg.
// k_hard    : per-batch exact top-k, 4-ary search on float bits, regs.
// k_final   : sum partials, write scalar.
// ws: slot[B*P] f32 conf_neg, npos[B] i32, pfo[B*N] i32,
//     locpart[B*nchunk] f32, pospart[B*nchunk] f32, hardsum[B] f32.

#define MAXN 16
#define MAXE 16   // max ceil(P/1024) supported by k_hard

__device__ __forceinline__ float sl1f(float d) {
    float ad = fabsf(d);
    return ad < 1.0f ? 0.5f * d * d : ad - 0.5f;
}

// One BLOCK (256 thr) per (b,n): argmax over P priors of IoU(box[b,n], prior).
// First-index ties: per-lane strict > over ascending p; reduce prefers larger
// v then smaller index.
__global__ __launch_bounds__(256) void k_bestprior(
    const float* __restrict__ boxes,   // [B,N,4] xy
    const float* __restrict__ priors,  // [P,4] cxcy
    int P, int N,
    int* __restrict__ pfo,             // [B*N]
    int* __restrict__ npos)            // [B] zeroed here
{
    __shared__ float rv[4];
    __shared__ int   riq[4];
    const int id = blockIdx.x;               // b*N + n
    const int tid = threadIdx.x;
    const int lane = tid & 63, wid = tid >> 6;

    if (tid == 0 && (id % N) == 0) npos[id / N] = 0;

    const float* bp = boxes + (size_t)id * 4;
    const float bx1 = bp[0], by1 = bp[1], bx2 = bp[2], by2 = bp[3];
    const float ba = (bx2 - bx1) * (by2 - by1);

    float v = -1.0f; int i = 0x7fffffff;
#pragma unroll 2
    for (int p = tid; p < P; p += 256) {
        float4 pr = ((const float4*)priors)[p];
        float px1 = pr.x - pr.z * 0.5f, py1 = pr.y - pr.w * 0.5f;
        float px2 = pr.x + pr.z * 0.5f, py2 = pr.y + pr.w * 0.5f;
        float parea = (px2 - px1) * (py2 - py1);
        float iw = fmaxf(fminf(bx2, px2) - fmaxf(bx1, px1), 0.0f);
        float ih = fmaxf(fminf(by2, py2) - fmaxf(by1, py1), 0.0f);
        float inter = iw * ih;
        float iou = inter / (ba + parea - inter);
        if (iou > v) { v = iou; i = p; }      // ascending p => first index
    }
#pragma unroll
    for (int off = 32; off > 0; off >>= 1) {
        float ov = __shfl_down(v, off);
        int   oi = __shfl_down(i, off);
        if (ov > v || (ov == v && oi < i)) { v = ov; i = oi; }
    }
    if (lane == 0) { rv[wid] = v; riq[wid] = i; }
    __syncthreads();
    if (tid == 0) {
        for (int w = 1; w < 4; w++) {
            float ov = rv[w]; int oi = riq[w];
            if (ov > v || (ov == v && oi < i)) { v = ov; i = oi; }
        }
        pfo[id] = i;
    }
}

// Thread per (b,p), grid (nchunk, B). Per thread: best object (argmax axis=0,
// first-index ties), override (ascending scan, last match wins = sequential
// scatter), label; CE from LDS-staged scores; SmoothL1 on positives.
__global__ __launch_bounds__(256) void k_fused(
    const float* __restrict__ plocs,   // [B,P,4]
    const float* __restrict__ scores,  // [B*P, C]
    const float* __restrict__ boxes,   // [B,N,4]
    const int*   __restrict__ labels,  // [B,N]
    const float* __restrict__ priors,  // [P,4]
    const int*   __restrict__ pfo,     // [B*N]
    int P, int C, int N, int nchunk,
    float* __restrict__ conf_out,      // [B,P] conf_neg
    int*   __restrict__ npos,          // [B] (atomic)
    float* __restrict__ locpart,       // [B*nchunk]
    float* __restrict__ pospart)       // [B*nchunk]
{
    extern __shared__ float sh[];      // 256*C floats (score rows)
    __shared__ float sx1[MAXN], sy1[MAXN], sx2[MAXN], sy2[MAXN], barea[MAXN];
    __shared__ int   blab[MAXN], spfo[MAXN];
    __shared__ float redf[4], redp[4];
    __shared__ int   redi[4];

    const int b = blockIdx.y;
    const int tid = threadIdx.x;
    const int lane = tid & 63, wid = tid >> 6;
    if (N > MAXN) N = MAXN;
    const int p0 = blockIdx.x * 256;
    const int rows = min(256, P - p0);

    if (tid < N) {
        const float* bp = boxes + ((size_t)b * N + tid) * 4;
        float x1 = bp[0], y1 = bp[1], x2 = bp[2], y2 = bp[3];
        sx1[tid] = x1; sy1[tid] = y1; sx2[tid] = x2; sy2[tid] = y2;
        barea[tid] = (x2 - x1) * (y2 - y1);
        blab[tid] = labels[(size_t)b * N + tid];
        spfo[tid] = pfo[b * N + tid];
    }

    // Stage this block's score rows, coalesced float4.
    // Base (b*P+p0)*C is 4-divisible here (P*C%4==0, 256*C%4==0).
    {
        const size_t f4base = ((size_t)b * P + p0) * C / 4;
        const int f4cnt = (rows * C + 3) / 4;
        const float4* __restrict__ s4 = (const float4*)scores;
        for (int j = tid; j < f4cnt; j += 256)
            ((float4*)sh)[j] = s4[f4base + j];
    }
    __syncthreads();

    const int p = p0 + tid;
    float locs = 0.0f, posc = 0.0f, conf = 0.0f;
    int np = 0;
    if (p < P) {
        float4 pr = ((const float4*)priors)[p];
        float px1 = pr.x - pr.z * 0.5f, py1 = pr.y - pr.w * 0.5f;
        float px2 = pr.x + pr.z * 0.5f, py2 = pr.y + pr.w * 0.5f;
        float parea = (px2 - px1) * (py2 - py1);
        float best = -1.0f; int bestn = 0;
#pragma unroll
        for (int n = 0; n < MAXN; n++) {
            if (n < N) {
                float iw = fmaxf(fminf(sx2[n], px2) - fmaxf(sx1[n], px1), 0.0f);
                float ih = fmaxf(fminf(sy2[n], py2) - fmaxf(sy1[n], py1), 0.0f);
                float inter = iw * ih;
                float iou = inter / (barea[n] + parea - inter);
                if (iou > best) { best = iou; bestn = n; }
            }
        }
        // override: last n with pfo[n]==p wins (matches sequential scatter)
#pragma unroll
        for (int n = 0; n < MAXN; n++) {
            if (n < N && spfo[n] == p) { bestn = n; best = 1.0f; }
        }
        const int lab = (best < 0.5f) ? 0 : blab[bestn];

        // CE from staged row
        const float* r = sh + tid * C;
        float m = -3.402823466e38f;
        for (int c = 0; c < C; c++) m = fmaxf(m, r[c]);
        float sum = 0.0f;
        for (int c = 0; c < C; c++) sum += __expf(r[c] - m);
        float ce = m + __logf(sum) - r[lab];   // -log_softmax[lab]

        if (lab != 0) {
            posc = ce; np = 1;                 // positive: goes to pos sum
            int n = bestn;
            float cx = (sx1[n] + sx2[n]) * 0.5f, cy = (sy1[n] + sy2[n]) * 0.5f;
            float w = sx2[n] - sx1[n], h = sy2[n] - sy1[n];
            float g0 = (cx - pr.x) / (pr.z / 10.0f);
            float g1 = (cy - pr.y) / (pr.w / 10.0f);
            float g2 = logf(w / pr.z) * 5.0f;
            float g3 = logf(h / pr.w) * 5.0f;
            float4 pl = ((const float4*)plocs)[(size_t)b * P + p];
            locs = sl1f(pl.x - g0) + sl1f(pl.y - g1) + sl1f(pl.z - g2) + sl1f(pl.w - g3);
        } else {
            conf = ce;                         // negative: candidate for top-k
        }
        conf_out[(size_t)b * P + p] = conf;
    }
#pragma unroll
    for (int off = 32; off > 0; off >>= 1) {
        locs += __shfl_down(locs, off);
        posc += __shfl_down(posc, off);
        np   += __shfl_down(np, off);
    }
    if (lane == 0) { redf[wid] = locs; redp[wid] = posc; redi[wid] = np; }
    __syncthreads();
    if (tid == 0) {
        float L = redf[0] + redf[1] + redf[2] + redf[3];
        float Pp = redp[0] + redp[1] + redp[2] + redp[3];
        int   c = redi[0] + redi[1] + redi[2] + redi[3];
        if (c) atomicAdd(&npos[b], c);            // int atomic: deterministic
        locpart[b * nchunk + blockIdx.x] = L;     // fixed slots: deterministic
        pospart[b * nchunk + blockIdx.x] = Pp;
    }
}

// Per-batch exact top-k sum. Values register-resident (MAXE per thread);
// 4-ary search on float bit patterns (conf >= 0 so uint order == float order).
__global__ __launch_bounds__(1024, 4) void k_hard(
    const float* __restrict__ conf,  // [B,P] conf_neg (>=0; 0 at positives)
    const int* __restrict__ npos,
    int P,
    float* __restrict__ hardsum)     // [B]
{
    __shared__ int   redi[16 * 3];
    __shared__ float redf2[16];
    __shared__ int   redi2[16];
    const int b = blockIdx.x, tid = threadIdx.x;
    const int lane = tid & 63, wid = tid >> 6;
    const int nthr = blockDim.x, nw = nthr >> 6;
    const int ne = (P + nthr - 1) / nthr;        // 9 for P=8732
    long long kk = (long long)npos[b] * 3;
    int k = kk > P ? P : (int)kk;
    if (k <= 0) {
        if (tid == 0) hardsum[b] = 0.0f;
        return;
    }

    // Coalesced load into registers; sentinel 0.0f (never selected: mid>=1,
    // and final pass uses strict > t with t>=0).
    unsigned e[MAXE];
#pragma unroll
    for (int j = 0; j < MAXE; j++) {
        int p = j * nthr + tid;
        e[j] = (j < ne && p < P) ? __float_as_uint(conf[(size_t)b * P + p]) : 0u;
    }

    // largest bit pattern t with count(x >= t) >= k == exact k-th largest.
    unsigned lo = 0u, hi = 0x7F800000u;
    while (lo < hi) {
        unsigned span = hi - lo;
        if (span >= 8) {
            unsigned q = span >> 2;
            unsigned m1 = lo + q, m2 = lo + 2 * q, m3 = lo + 3 * q;
            int c1 = 0, c2 = 0, c3 = 0;
#pragma unroll
            for (int j = 0; j < MAXE; j++) {
                if (j < ne) {
                    unsigned v = e[j];
                    c1 += (int)__popcll(__ballot(v >= m1));
                    c2 += (int)__popcll(__ballot(v >= m2));
                    c3 += (int)__popcll(__ballot(v >= m3));
                }
            }
            if (lane == 0) {
                redi[wid * 3 + 0] = c1; redi[wid * 3 + 1] = c2; redi[wid * 3 + 2] = c3;
            }
            __syncthreads();
            int C1 = 0, C2 = 0, C3 = 0;
            for (int w = 0; w < nw; w++) {
                C1 += redi[w * 3 + 0]; C2 += redi[w * 3 + 1]; C3 += redi[w * 3 + 2];
            }
            __syncthreads();
            if      (C3 >= k) lo = m3;
            else if (C2 >= k) { lo = m2; hi = m3 - 1; }
            else if (C1 >= k) { lo = m1; hi = m2 - 1; }
            else              hi = m1 - 1;
        } else {
            unsigned mid = lo + ((span + 1) >> 1);
            int c = 0;
#pragma unroll
            for (int j = 0; j < MAXE; j++)
                if (j < ne) c += (int)__popcll(__ballot(e[j] >= mid));
            if (lane == 0) redi[wid * 3] = c;
            __syncthreads();
            int Cc = 0;
            for (int w = 0; w < nw; w++) Cc += redi[w * 3];
            __syncthreads();
            if (Cc >= k) lo = mid; else hi = mid - 1;
        }
    }

    float t = __uint_as_float(lo);
    float sgt = 0.0f; int cgt = 0;
#pragma unroll
    for (int j = 0; j < MAXE; j++) {
        if (j < ne) {
            float v = __uint_as_float(e[j]);
            if (v > t) { sgt += v; cgt++; }
        }
    }
#pragma unroll
    for (int off = 32; off > 0; off >>= 1) {
        sgt += __shfl_down(sgt, off);
        cgt += __shfl_down(cgt, off);
    }
    if (lane == 0) { redf2[wid] = sgt; redi2[wid] = cgt; }
    __syncthreads();
    if (tid == 0) {
        float S = 0.0f; int Cg = 0;
        for (int w = 0; w < nw; w++) { S += redf2[w]; Cg += redi2[w]; }
        hardsum[b] = S + (float)(k - Cg) * t;   // ties at t handled exactly
    }
}

__global__ __launch_bounds__(1024) void k_final(
    const int* __restrict__ npos, const float* __restrict__ locpart,
    const float* __restrict__ pospart, const float* __restrict__ hardsum,
    int B, int nloc, float* __restrict__ out)
{
    const int tid = threadIdx.x, lane = tid & 63, wid = tid >> 6;
    __shared__ float rf[3 * 16];
    __shared__ int   ri[16];
    float lp = 0, pp = 0, hp = 0; int np = 0;
    for (int i = tid; i < B; i += 1024) { np += npos[i]; hp += hardsum[i]; }
    for (int i = tid; i < nloc; i += 1024) { lp += locpart[i]; pp += pospart[i]; }
#pragma unroll
    for (int off = 32; off > 0; off >>= 1) {
        np += __shfl_down(np, off); lp += __shfl_down(lp, off);
        pp += __shfl_down(pp, off); hp += __shfl_down(hp, off);
    }
    if (lane == 0) { ri[wid] = np; rf[wid] = lp; rf[16 + wid] = pp; rf[32 + wid] = hp; }
    __syncthreads();
    if (tid == 0) {
        int nw = (int)(blockDim.x >> 6);
        float L = 0, Pp = 0, H = 0; int Np = 0;
        for (int w = 0; w < nw; w++) { Np += ri[w]; L += rf[w]; Pp += rf[16 + w]; H += rf[32 + w]; }
        float npf = (float)Np;
        out[0] = (H + Pp) / npf + L / (npf * 4.0f);
    }
}

extern "C" void kernel_launch(void* const* d_in, const int* in_sizes, int n_in,
                              void* d_out, int out_size, void* d_ws, size_t ws_size,
                              hipStream_t stream)
{
    const float* plocs  = (const float*)d_in[0];
    const float* scores = (const float*)d_in[1];
    const float* boxes  = (const float*)d_in[2];
    const int*   labels = (const int*)d_in[3];
    const float* priors = (const float*)d_in[4];

    int P = in_sizes[4] / 4;
    int B = in_sizes[0] / (P * 4);
    int C = in_sizes[1] / (in_sizes[0] / 4);
    int N = in_sizes[3] / B;
    int nchunk = (P + 255) / 256;
    int BN = B * N;

    char* w = (char*)d_ws;
    float* slot    = (float*)w;  w += (size_t)B * P * sizeof(float);
    int*   npos    = (int*)w;    w += (size_t)B * sizeof(int);
    int*   pfo     = (int*)w;    w += (size_t)BN * sizeof(int);
    float* locpart = (float*)w;  w += (size_t)B * nchunk * sizeof(float);
    float* pospart = (float*)w;  w += (size_t)B * nchunk * sizeof(float);
    float* hardsum = (float*)w;

    k_bestprior<<<BN, 256, 0, stream>>>(boxes, priors, P, N, pfo, npos);

    dim3 ga(nchunk, B);
    size_t smf = (size_t)256 * C * sizeof(float);
    k_fused<<<ga, 256, smf, stream>>>(plocs, scores, boxes, labels, priors, pfo,
                                      P, C, N, nchunk, slot, npos, locpart, pospart);

    k_hard<<<B, 1024, 0, stream>>>(slot, npos, P, hardsum);

    k_final<<<1, 1024, 0, stream>>>(npos, locpart, pospart, hardsum,
                                    B, B * nchunk, (float*)d_out);
}